// Round 1
// baseline (573.320 us; speedup 1.0000x reference)
//
#include <hip/hip_runtime.h>

typedef __attribute__((ext_vector_type(8))) short short8;
typedef __attribute__((ext_vector_type(4))) float floatx4;

#define MFMA16(a, b, c) __builtin_amdgcn_mfma_f32_16x16x32_bf16((a), (b), (c), 0, 0, 0)

#define LAMBDA_INIT_F 0.777870099559256f
#define ONE_MINUS_LAMBDA_F 0.222129900440744f

static __device__ __forceinline__ unsigned short f2bf(float f) {
  union { float f; unsigned int u; } v; v.f = f;
  unsigned int r = v.u + 0x7FFFu + ((v.u >> 16) & 1u);
  return (unsigned short)(r >> 16);
}

// ---------------- f32 -> bf16 conversion ----------------
__global__ __launch_bounds__(256) void cvt_f32_bf16(const float* __restrict__ in,
                                                    unsigned short* __restrict__ out,
                                                    int n) {
  int i = blockIdx.x * 256 + threadIdx.x;
  if (i < n) out[i] = f2bf(in[i]);
}

// ---------------- GEMM: C = A (MxK, bf16) * Bt^T (Bt is NxK, bf16) + bias ----------------
// MODE 1: write Q/K head layout  out[((b*32+h2)*1024 + s)*32 + d], h2=col>>5, d=col&31
// MODE 2: write V transposed     out[((b*16+h)*64 + d)*1024 + s],  h=col>>6,  d=col&63
// MODE 3: write f32 row-major    out[row*N + col]
template <int MODE>
__global__ __launch_bounds__(256) void gemm_bt(const unsigned short* __restrict__ A,
                                               const unsigned short* __restrict__ Bt,
                                               const float* __restrict__ bias,
                                               void* __restrict__ out,
                                               int M, int N, int K) {
  __shared__ unsigned short As[64][40];
  __shared__ unsigned short Bs[64][40];
  const int tid = threadIdx.x;
  const int m0 = blockIdx.y * 64;
  const int n0 = blockIdx.x * 64;
  const int w = tid >> 6, lane = tid & 63;
  const int wm = (w >> 1) * 32, wn = (w & 1) * 32;
  const int lrow = lane & 15, quad = lane >> 4;

  floatx4 acc[2][2];
  for (int i = 0; i < 2; i++)
    for (int j = 0; j < 2; j++)
      acc[i][j] = (floatx4){0.f, 0.f, 0.f, 0.f};

  const int ldr = tid >> 2;        // 0..63
  const int ldc = (tid & 3) * 8;   // 0,8,16,24

  for (int k0 = 0; k0 < K; k0 += 32) {
    short8 av = *(const short8*)(A + (size_t)(m0 + ldr) * K + k0 + ldc);
    short8 bv = *(const short8*)(Bt + (size_t)(n0 + ldr) * K + k0 + ldc);
    *(short8*)(&As[ldr][ldc]) = av;
    *(short8*)(&Bs[ldr][ldc]) = bv;
    __syncthreads();
    short8 a0 = *(const short8*)(&As[wm + lrow][quad * 8]);
    short8 a1 = *(const short8*)(&As[wm + 16 + lrow][quad * 8]);
    short8 b0 = *(const short8*)(&Bs[wn + lrow][quad * 8]);
    short8 b1 = *(const short8*)(&Bs[wn + 16 + lrow][quad * 8]);
    acc[0][0] = MFMA16(a0, b0, acc[0][0]);
    acc[0][1] = MFMA16(a0, b1, acc[0][1]);
    acc[1][0] = MFMA16(a1, b0, acc[1][0]);
    acc[1][1] = MFMA16(a1, b1, acc[1][1]);
    __syncthreads();
  }

  for (int mi = 0; mi < 2; mi++)
    for (int ni = 0; ni < 2; ni++)
      for (int r = 0; r < 4; r++) {
        int row = m0 + wm + mi * 16 + quad * 4 + r;
        int col = n0 + wn + ni * 16 + lrow;
        float v = acc[mi][ni][r] + bias[col];
        if (MODE == 1) {
          int b = row >> 10, s = row & 1023, h2 = col >> 5, d = col & 31;
          ((unsigned short*)out)[((((size_t)(b * 32 + h2)) << 10) + s) * 32 + d] = f2bf(v);
        } else if (MODE == 2) {
          int b = row >> 10, s = row & 1023, h = col >> 6, d = col & 63;
          ((unsigned short*)out)[((((size_t)(b * 16 + h)) * 64 + d) << 10) + s] = f2bf(v);
        } else {
          ((float*)out)[(size_t)row * N + col] = v;
        }
      }
}

// ---------------- attention stats: per-row max & sum of exp ----------------
// wave handles one (b, h, 16-row chunk); both sub-heads 2h, 2h+1
__global__ __launch_bounds__(256) void attn_stats(const unsigned short* __restrict__ qh,
                                                  const unsigned short* __restrict__ kh,
                                                  float* __restrict__ stat_m,
                                                  float* __restrict__ stat_l) {
  const int W = blockIdx.x * 4 + (threadIdx.x >> 6);
  const int lane = threadIdx.x & 63;
  const int chunk = W & 63;
  const int bh = W >> 6;  // 0..63
  const int b = bh >> 4, h = bh & 15;
  const int lrow = lane & 15, quad = lane >> 4;
  const int r0 = chunk * 16;

  const unsigned short* q1 = qh + ((((size_t)(b * 32 + 2 * h)) << 10) + r0) * 32;
  const unsigned short* q2 = qh + ((((size_t)(b * 32 + 2 * h + 1)) << 10) + r0) * 32;
  const unsigned short* k1 = kh + (((size_t)(b * 32 + 2 * h)) << 10) * 32;
  const unsigned short* k2 = kh + (((size_t)(b * 32 + 2 * h + 1)) << 10) * 32;

  short8 a1 = *(const short8*)(q1 + lrow * 32 + quad * 8);
  short8 a2 = *(const short8*)(q2 + lrow * 32 + quad * 8);

  float m1[4], l1[4], m2[4], l2[4];
  for (int r = 0; r < 4; r++) { m1[r] = -1e30f; l1[r] = 0.f; m2[r] = -1e30f; l2[r] = 0.f; }

  for (int c = 0; c < 64; c++) {
    short8 bk1 = *(const short8*)(k1 + (c * 16 + lrow) * 32 + quad * 8);
    short8 bk2 = *(const short8*)(k2 + (c * 16 + lrow) * 32 + quad * 8);
    floatx4 z = (floatx4){0.f, 0.f, 0.f, 0.f};
    floatx4 s1 = MFMA16(a1, bk1, z);
    floatx4 s2 = MFMA16(a2, bk2, z);
    for (int r = 0; r < 4; r++) {
      float v1 = s1[r] * 0.125f;
      float nm1 = fmaxf(m1[r], v1);
      l1[r] = l1[r] * __expf(m1[r] - nm1) + __expf(v1 - nm1);
      m1[r] = nm1;
      float v2 = s2[r] * 0.125f;
      float nm2 = fmaxf(m2[r], v2);
      l2[r] = l2[r] * __expf(m2[r] - nm2) + __expf(v2 - nm2);
      m2[r] = nm2;
    }
  }
  // reduce across the 16 lanes holding different columns of the same rows
  for (int off = 1; off < 16; off <<= 1) {
    for (int r = 0; r < 4; r++) {
      float om = __shfl_xor(m1[r], off);
      float ol = __shfl_xor(l1[r], off);
      float nm = fmaxf(m1[r], om);
      l1[r] = l1[r] * __expf(m1[r] - nm) + ol * __expf(om - nm);
      m1[r] = nm;
      om = __shfl_xor(m2[r], off);
      ol = __shfl_xor(l2[r], off);
      nm = fmaxf(m2[r], om);
      l2[r] = l2[r] * __expf(m2[r] - nm) + ol * __expf(om - nm);
      m2[r] = nm;
    }
  }
  if (lrow == 0) {
    for (int r = 0; r < 4; r++) {
      int row = r0 + quad * 4 + r;
      size_t i1 = (((size_t)(b * 32 + 2 * h)) << 10) + row;
      size_t i2 = (((size_t)(b * 32 + 2 * h + 1)) << 10) + row;
      stat_m[i1] = m1[r]; stat_l[i1] = l1[r];
      stat_m[i2] = m2[r]; stat_l[i2] = l2[r];
    }
  }
}

// ---------------- pass 2: diff_w write + PV + RMSNorm ----------------
__global__ __launch_bounds__(256) void attn_pass2(const unsigned short* __restrict__ qh,
                                                  const unsigned short* __restrict__ kh,
                                                  const unsigned short* __restrict__ vt,
                                                  const float* __restrict__ stat_m,
                                                  const float* __restrict__ stat_l,
                                                  const float* __restrict__ lq1,
                                                  const float* __restrict__ lk1,
                                                  const float* __restrict__ lq2,
                                                  const float* __restrict__ lk2,
                                                  const float* __restrict__ subln,
                                                  float* __restrict__ diffw,
                                                  unsigned short* __restrict__ attn_out) {
  __shared__ unsigned short ds[4][16][40];
  const int wid = threadIdx.x >> 6;
  const int W = blockIdx.x * 4 + wid;
  const int lane = threadIdx.x & 63;
  const int chunk = W & 63;
  const int bh = W >> 6;
  const int b = bh >> 4, h = bh & 15;
  const int lrow = lane & 15, quad = lane >> 4;
  const int r0 = chunk * 16;

  float sl1 = 0.f, sl2 = 0.f;
  for (int i = 0; i < 32; i++) { sl1 += lq1[i] * lk1[i]; sl2 += lq2[i] * lk2[i]; }
  const float lam = __expf(sl1) - __expf(sl2) + LAMBDA_INIT_F;

  const unsigned short* q1 = qh + ((((size_t)(b * 32 + 2 * h)) << 10) + r0) * 32;
  const unsigned short* q2 = qh + ((((size_t)(b * 32 + 2 * h + 1)) << 10) + r0) * 32;
  const unsigned short* k1 = kh + (((size_t)(b * 32 + 2 * h)) << 10) * 32;
  const unsigned short* k2 = kh + (((size_t)(b * 32 + 2 * h + 1)) << 10) * 32;
  const unsigned short* vth = vt + (((size_t)(b * 16 + h)) << 16);  // *64*1024

  short8 a1 = *(const short8*)(q1 + lrow * 32 + quad * 8);
  short8 a2 = *(const short8*)(q2 + lrow * 32 + quad * 8);

  float em1[4], il1[4], em2[4], il2[4];
  for (int r = 0; r < 4; r++) {
    int row = r0 + quad * 4 + r;
    size_t i1 = (((size_t)(b * 32 + 2 * h)) << 10) + row;
    size_t i2 = (((size_t)(b * 32 + 2 * h + 1)) << 10) + row;
    em1[r] = stat_m[i1]; il1[r] = 1.f / stat_l[i1];
    em2[r] = stat_m[i2]; il2[r] = 1.f / stat_l[i2];
  }

  floatx4 accO[4];
  for (int nt = 0; nt < 4; nt++) accO[nt] = (floatx4){0.f, 0.f, 0.f, 0.f};

  float* dwbase = diffw + (((size_t)bh) << 20) + (size_t)r0 * 1024;

  for (int c2 = 0; c2 < 32; c2++) {
    for (int cc = 0; cc < 2; cc++) {
      int c = c2 * 2 + cc;
      short8 bk1 = *(const short8*)(k1 + (c * 16 + lrow) * 32 + quad * 8);
      short8 bk2 = *(const short8*)(k2 + (c * 16 + lrow) * 32 + quad * 8);
      floatx4 z = (floatx4){0.f, 0.f, 0.f, 0.f};
      floatx4 s1 = MFMA16(a1, bk1, z);
      floatx4 s2 = MFMA16(a2, bk2, z);
      for (int r = 0; r < 4; r++) {
        float p1 = __expf(s1[r] * 0.125f - em1[r]) * il1[r];
        float p2 = __expf(s2[r] * 0.125f - em2[r]) * il2[r];
        float d = p1 - lam * p2;
        dwbase[(size_t)(quad * 4 + r) * 1024 + c * 16 + lrow] = d;
        ds[wid][quad * 4 + r][cc * 16 + lrow] = f2bf(d);
      }
    }
    // same-wave LDS round trip: C-layout diff -> A-operand layout
    short8 ad = *(const short8*)(&ds[wid][lrow][quad * 8]);
    for (int nt = 0; nt < 4; nt++) {
      short8 bv = *(const short8*)(vth + (((size_t)(nt * 16 + lrow)) << 10) + c2 * 32 + quad * 8);
      accO[nt] = MFMA16(ad, bv, accO[nt]);
    }
  }

  // RMSNorm over head dim (64) + subln + (1 - lambda_init)
  float rs[4];
  for (int r = 0; r < 4; r++) {
    float s = 0.f;
    for (int nt = 0; nt < 4; nt++) s += accO[nt][r] * accO[nt][r];
    for (int off = 1; off < 16; off <<= 1) s += __shfl_xor(s, off);
    rs[r] = rsqrtf(s * (1.f / 64.f) + 1e-5f);
  }
  for (int r = 0; r < 4; r++) {
    int row = r0 + quad * 4 + r;
    for (int nt = 0; nt < 4; nt++) {
      int d = nt * 16 + lrow;
      float v = accO[nt][r] * rs[r] * subln[d] * ONE_MINUS_LAMBDA_F;
      attn_out[((((size_t)b) << 10) + row) * 1024 + h * 64 + d] = f2bf(v);
    }
  }
}

extern "C" void kernel_launch(void* const* d_in, const int* in_sizes, int n_in,
                              void* d_out, int out_size, void* d_ws, size_t ws_size,
                              hipStream_t stream) {
  (void)in_sizes; (void)n_in; (void)out_size; (void)ws_size;
  const float* hs = (const float*)d_in[0];
  const float* q_w = (const float*)d_in[1];
  const float* q_b = (const float*)d_in[2];
  const float* k_w = (const float*)d_in[3];
  const float* k_b = (const float*)d_in[4];
  const float* v_w = (const float*)d_in[5];
  const float* v_b = (const float*)d_in[6];
  const float* o_w = (const float*)d_in[7];
  const float* o_b = (const float*)d_in[8];
  const float* lq1 = (const float*)d_in[9];
  const float* lk1 = (const float*)d_in[10];
  const float* lq2 = (const float*)d_in[11];
  const float* lk2 = (const float*)d_in[12];
  const float* subln = (const float*)d_in[13];

  char* ws = (char*)d_ws;
  unsigned short* hs_bf = (unsigned short*)(ws + 0);
  unsigned short* qw_bf = (unsigned short*)(ws + 8388608);
  unsigned short* kw_bf = (unsigned short*)(ws + 10485760);
  unsigned short* vw_bf = (unsigned short*)(ws + 12582912);
  unsigned short* ow_bf = (unsigned short*)(ws + 14680064);
  unsigned short* q_h = (unsigned short*)(ws + 16777216);
  unsigned short* k_h = (unsigned short*)(ws + 25165824);
  unsigned short* v_t = (unsigned short*)(ws + 33554432);
  unsigned short* attnb = (unsigned short*)(ws + 41943040);
  float* stat_m = (float*)(ws + 50331648);
  float* stat_l = (float*)(ws + 50855936);

  cvt_f32_bf16<<<16384, 256, 0, stream>>>(hs, hs_bf, 4194304);
  cvt_f32_bf16<<<4096, 256, 0, stream>>>(q_w, qw_bf, 1048576);
  cvt_f32_bf16<<<4096, 256, 0, stream>>>(k_w, kw_bf, 1048576);
  cvt_f32_bf16<<<4096, 256, 0, stream>>>(v_w, vw_bf, 1048576);
  cvt_f32_bf16<<<4096, 256, 0, stream>>>(o_w, ow_bf, 1048576);

  gemm_bt<1><<<dim3(16, 64), 256, 0, stream>>>(hs_bf, qw_bf, q_b, (void*)q_h, 4096, 1024, 1024);
  gemm_bt<1><<<dim3(16, 64), 256, 0, stream>>>(hs_bf, kw_bf, k_b, (void*)k_h, 4096, 1024, 1024);
  gemm_bt<2><<<dim3(16, 64), 256, 0, stream>>>(hs_bf, vw_bf, v_b, (void*)v_t, 4096, 1024, 1024);

  attn_stats<<<1024, 256, 0, stream>>>(q_h, k_h, stat_m, stat_l);

  float* outf = (float*)d_out;
  attn_pass2<<<1024, 256, 0, stream>>>(q_h, k_h, v_t, stat_m, stat_l,
                                       lq1, lk1, lq2, lk2, subln,
                                       outf + 4194304, attnb);

  gemm_bt<3><<<dim3(16, 64), 256, 0, stream>>>(attnb, ow_bf, o_b, (void*)outf, 4096, 1024, 1024);
}

// Round 3
// 537.997 us; speedup vs baseline: 1.0657x; 1.0657x over previous
//
#include <hip/hip_runtime.h>

typedef __attribute__((ext_vector_type(8))) short short8;
typedef __attribute__((ext_vector_type(4))) float floatx4;

#define MFMA16(a, b, c) __builtin_amdgcn_mfma_f32_16x16x32_bf16((a), (b), (c), 0, 0, 0)

#define LAMBDA_INIT_F 0.777870099559256f
#define ONE_MINUS_LAMBDA_F 0.222129900440744f

// async global->LDS, 16B per lane; LDS dest = wave-uniform base + lane*16
#define GLL(g, l)                                                              \
  __builtin_amdgcn_global_load_lds(                                            \
      (const __attribute__((address_space(1))) void*)(g),                      \
      (__attribute__((address_space(3))) void*)(l), 16, 0, 0)

static __device__ __forceinline__ unsigned short f2bf(float f) {
  union { float f; unsigned int u; } v; v.f = f;
  unsigned int r = v.u + 0x7FFFu + ((v.u >> 16) & 1u);
  return (unsigned short)(r >> 16);
}

// ---------------- f32 -> bf16 conversion (vectorized) ----------------
__global__ __launch_bounds__(256) void cvt_f32_bf16(const float* __restrict__ in,
                                                    unsigned short* __restrict__ out,
                                                    int n4) {
  int i = blockIdx.x * 256 + threadIdx.x;
  if (i < n4) {
    float4 v = ((const float4*)in)[i];
    unsigned short o0 = f2bf(v.x), o1 = f2bf(v.y), o2 = f2bf(v.z), o3 = f2bf(v.w);
    ushort2 a = {o0, o1}, b = {o2, o3};
    ((ushort2*)out)[i * 2] = a;
    ((ushort2*)out)[i * 2 + 1] = b;
  }
}

// ---------------- 128x128 GEMM core (m97 pattern): C = A * Bt^T ----------------
// A: M x 1024 bf16 row-major; Bt: N x 1024 bf16 row-major. K fixed = 1024, BK=32.
__device__ __forceinline__ void gemm128_core(const unsigned short* __restrict__ A,
                                             const unsigned short* __restrict__ Bt,
                                             unsigned short* As, unsigned short* Bs,
                                             int m0, int n0, floatx4 (&acc)[4][4]) {
  const int tid = threadIdx.x;
  const int w = tid >> 6, lane = tid & 63;
  const int lrow = lane & 15, quad = lane >> 4;
  const int wm = (w >> 1) * 64, wn = (w & 1) * 64;

#pragma unroll
  for (int i = 0; i < 4; i++)
#pragma unroll
    for (int j = 0; j < 4; j++)
      acc[i][j] = (floatx4){0.f, 0.f, 0.f, 0.f};

  const int ar = tid >> 2;          // 0..63
  const int ac = (tid & 3) * 8;     // 0,8,16,24
  const unsigned short* ga = A + (size_t)(m0 + ar) * 1024 + ac;
  const unsigned short* gb = Bt + (size_t)(n0 + ar) * 1024 + ac;
  unsigned short* la = As + w * 512;   // wave base (bytes: w*1024)
  unsigned short* lb = Bs + w * 512;

  for (int k0 = 0; k0 < 1024; k0 += 32) {
    GLL(ga + k0, la);                       // rows 0..63
    GLL(ga + k0 + 64 * 1024, la + 2048);    // rows 64..127
    GLL(gb + k0, lb);
    GLL(gb + k0 + 64 * 1024, lb + 2048);
    __syncthreads();
    short8 af[4], bfr[4];
#pragma unroll
    for (int i = 0; i < 4; i++)
      af[i] = *(const short8*)(As + (wm + i * 16 + lrow) * 32 + quad * 8);
#pragma unroll
    for (int j = 0; j < 4; j++)
      bfr[j] = *(const short8*)(Bs + (wn + j * 16 + lrow) * 32 + quad * 8);
#pragma unroll
    for (int i = 0; i < 4; i++)
#pragma unroll
      for (int j = 0; j < 4; j++)
        acc[i][j] = MFMA16(af[i], bfr[j], acc[i][j]);
    __syncthreads();
  }
}

// ---------------- fused QKV projection GEMM ----------------
// grid.x: 0..7 -> Q, 8..15 -> K, 16..23 -> V ; grid.y: M/128 = 32
// Q/K out: [b, 2H, s, 32] bf16 head layout. V out: natural [b*s, 1024] bf16.
__global__ __launch_bounds__(256, 2) void gemm_qkv(const unsigned short* __restrict__ A,
                                                   const unsigned short* __restrict__ qw,
                                                   const unsigned short* __restrict__ kw,
                                                   const unsigned short* __restrict__ vw,
                                                   const float* __restrict__ qb,
                                                   const float* __restrict__ kb,
                                                   const float* __restrict__ vb,
                                                   unsigned short* __restrict__ qh,
                                                   unsigned short* __restrict__ kh,
                                                   unsigned short* __restrict__ vnat) {
  __shared__ unsigned short As[128 * 32];
  __shared__ unsigned short Bs[128 * 32];
  const int m0 = blockIdx.y * 128;
  const int nglob = blockIdx.x * 128;
  const int wsel = nglob >> 10;
  const int nloc = nglob & 1023;
  const unsigned short* Bt = (wsel == 0) ? qw : ((wsel == 1) ? kw : vw);
  const float* bias = (wsel == 0) ? qb : ((wsel == 1) ? kb : vb);

  floatx4 acc[4][4];
  gemm128_core(A, Bt, As, Bs, m0, nloc, acc);

  const int tid = threadIdx.x;
  const int w = tid >> 6, lane = tid & 63;
  const int lrow = lane & 15, quad = lane >> 4;
  const int wm = (w >> 1) * 64, wn = (w & 1) * 64;

#pragma unroll
  for (int i = 0; i < 4; i++)
#pragma unroll
    for (int j = 0; j < 4; j++) {
      int col = nloc + wn + j * 16 + lrow;
      float bcol = bias[col];
#pragma unroll
      for (int r = 0; r < 4; r++) {
        int row = m0 + wm + i * 16 + quad * 4 + r;
        float v = acc[i][j][r] + bcol;
        if (wsel < 2) {
          int b = row >> 10, s = row & 1023, h2 = col >> 5, d = col & 31;
          unsigned short* o = (wsel == 0) ? qh : kh;
          o[((((size_t)(b * 32 + h2)) << 10) + s) * 32 + d] = f2bf(v);
        } else {
          vnat[(size_t)row * 1024 + col] = f2bf(v);
        }
      }
    }
}

// ---------------- O projection GEMM (f32 out) ----------------
__global__ __launch_bounds__(256, 2) void gemm_o(const unsigned short* __restrict__ A,
                                                 const unsigned short* __restrict__ ow,
                                                 const float* __restrict__ ob,
                                                 float* __restrict__ out) {
  __shared__ unsigned short As[128 * 32];
  __shared__ unsigned short Bs[128 * 32];
  const int m0 = blockIdx.y * 128;
  const int n0 = blockIdx.x * 128;

  floatx4 acc[4][4];
  gemm128_core(A, ow, As, Bs, m0, n0, acc);

  const int tid = threadIdx.x;
  const int w = tid >> 6, lane = tid & 63;
  const int lrow = lane & 15, quad = lane >> 4;
  const int wm = (w >> 1) * 64, wn = (w & 1) * 64;

#pragma unroll
  for (int i = 0; i < 4; i++)
#pragma unroll
    for (int j = 0; j < 4; j++) {
      int col = n0 + wn + j * 16 + lrow;
      float bcol = ob[col];
#pragma unroll
      for (int r = 0; r < 4; r++) {
        int row = m0 + wm + i * 16 + quad * 4 + r;
        out[(size_t)row * 1024 + col] = acc[i][j][r] + bcol;
      }
    }
}

// ---------------- V transpose: [b,s,h,d] -> [b,h,d,s] ----------------
__global__ __launch_bounds__(256) void transpose_v(const unsigned short* __restrict__ vn,
                                                   unsigned short* __restrict__ vt) {
  __shared__ unsigned int tile[64][65];
  const int t = threadIdx.x;
  const int bh = blockIdx.y, b = bh >> 4, h = bh & 15;
  const int s0 = blockIdx.x * 64;
#pragma unroll
  for (int i = 0; i < 2; i++) {
    int r = i * 32 + (t >> 3);
    int c8 = (t & 7) * 8;
    short8 v = *(const short8*)(vn + ((size_t)(b * 1024 + s0 + r)) * 1024 + h * 64 + c8);
#pragma unroll
    for (int j = 0; j < 8; j++) tile[r][c8 + j] = (unsigned short)v[j];
  }
  __syncthreads();
  const int w = t >> 6, lane = t & 63;
#pragma unroll
  for (int dd = 0; dd < 16; dd++) {
    int d = w * 16 + dd;
    unsigned short u = (unsigned short)tile[lane][d];
    vt[(((size_t)(b * 16 + h)) * 64 + d) * 1024 + s0 + lane] = u;
  }
}

// ---------------- single-pass fused differential attention ----------------
// block = 4 waves = one (b,h,16-row chunk); wave w owns cols [w*256, w*256+256)
__global__ __launch_bounds__(256) void attn_fused(const unsigned short* __restrict__ qh,
                                                  const unsigned short* __restrict__ kh,
                                                  const unsigned short* __restrict__ vt,
                                                  const float* __restrict__ lq1,
                                                  const float* __restrict__ lk1,
                                                  const float* __restrict__ lq2,
                                                  const float* __restrict__ lk2,
                                                  const float* __restrict__ subln,
                                                  float* __restrict__ diffw,
                                                  unsigned short* __restrict__ attnb) {
  __shared__ float redm[4][2][16];
  __shared__ float redl[4][2][16];
  __shared__ unsigned short dsA[4][16][40];
  __shared__ float ored[4][16][64];

  const int tid = threadIdx.x;
  const int w = tid >> 6, lane = tid & 63;
  const int lrow = lane & 15, quad = lane >> 4;
  const int blk = blockIdx.x;
  const int chunk = blk & 63, bh = blk >> 6;
  const int b = bh >> 4, h = bh & 15;
  const int r0 = chunk * 16;
  const int cbase = w * 256;

  float sl1 = 0.f, sl2 = 0.f;
  for (int i = 0; i < 32; i++) { sl1 += lq1[i] * lk1[i]; sl2 += lq2[i] * lk2[i]; }
  const float lam = __expf(sl1) - __expf(sl2) + LAMBDA_INIT_F;

  const unsigned short* q1 = qh + ((((size_t)(b * 32 + 2 * h)) << 10) + r0) * 32;
  const unsigned short* q2 = q1 + (32u << 10);          // next sub-head: +S*HD2 = +32768
  const unsigned short* k1 = kh + (((size_t)(b * 32 + 2 * h)) << 10) * 32;
  const unsigned short* k2 = k1 + (32u << 10);          // FIX (was *32 too large): +S*HD2
  const unsigned short* vth = vt + (((size_t)(b * 16 + h)) << 16);

  short8 a1 = *(const short8*)(q1 + lrow * 32 + quad * 8);
  short8 a2 = *(const short8*)(q2 + lrow * 32 + quad * 8);

  floatx4 s1a[16], s2a[16];
  float m1[4], m2[4];
#pragma unroll
  for (int r = 0; r < 4; r++) { m1[r] = -1e30f; m2[r] = -1e30f; }

  const floatx4 zero = (floatx4){0.f, 0.f, 0.f, 0.f};

#pragma unroll
  for (int ct = 0; ct < 16; ct++) {
    short8 bk = *(const short8*)(k1 + (size_t)(cbase + ct * 16 + lrow) * 32 + quad * 8);
    floatx4 s = MFMA16(a1, bk, zero);
#pragma unroll
    for (int r = 0; r < 4; r++) {
      float v = s[r] * 0.125f;
      s1a[ct][r] = v;
      m1[r] = fmaxf(m1[r], v);
    }
  }
#pragma unroll
  for (int ct = 0; ct < 16; ct++) {
    short8 bk = *(const short8*)(k2 + (size_t)(cbase + ct * 16 + lrow) * 32 + quad * 8);
    floatx4 s = MFMA16(a2, bk, zero);
#pragma unroll
    for (int r = 0; r < 4; r++) {
      float v = s[r] * 0.125f;
      s2a[ct][r] = v;
      m2[r] = fmaxf(m2[r], v);
    }
  }

  // wave-level max over the 16 column-lanes
#pragma unroll
  for (int off = 1; off < 16; off <<= 1) {
#pragma unroll
    for (int r = 0; r < 4; r++) {
      m1[r] = fmaxf(m1[r], __shfl_xor(m1[r], off));
      m2[r] = fmaxf(m2[r], __shfl_xor(m2[r], off));
    }
  }
  if (lrow == 0) {
#pragma unroll
    for (int r = 0; r < 4; r++) {
      redm[w][0][quad * 4 + r] = m1[r];
      redm[w][1][quad * 4 + r] = m2[r];
    }
  }
  __syncthreads();
  float mf1[4], mf2[4];
#pragma unroll
  for (int r = 0; r < 4; r++) {
    int rr = quad * 4 + r;
    mf1[r] = fmaxf(fmaxf(redm[0][0][rr], redm[1][0][rr]), fmaxf(redm[2][0][rr], redm[3][0][rr]));
    mf2[r] = fmaxf(fmaxf(redm[0][1][rr], redm[1][1][rr]), fmaxf(redm[2][1][rr], redm[3][1][rr]));
  }

  float l1[4] = {0.f, 0.f, 0.f, 0.f}, l2[4] = {0.f, 0.f, 0.f, 0.f};
#pragma unroll
  for (int ct = 0; ct < 16; ct++) {
#pragma unroll
    for (int r = 0; r < 4; r++) {
      float e1 = __expf(s1a[ct][r] - mf1[r]);
      s1a[ct][r] = e1;
      l1[r] += e1;
      float e2 = __expf(s2a[ct][r] - mf2[r]);
      s2a[ct][r] = e2;
      l2[r] += e2;
    }
  }
#pragma unroll
  for (int off = 1; off < 16; off <<= 1) {
#pragma unroll
    for (int r = 0; r < 4; r++) {
      l1[r] += __shfl_xor(l1[r], off);
      l2[r] += __shfl_xor(l2[r], off);
    }
  }
  if (lrow == 0) {
#pragma unroll
    for (int r = 0; r < 4; r++) {
      redl[w][0][quad * 4 + r] = l1[r];
      redl[w][1][quad * 4 + r] = l2[r];
    }
  }
  __syncthreads();
  float il1[4], il2[4];
#pragma unroll
  for (int r = 0; r < 4; r++) {
    int rr = quad * 4 + r;
    il1[r] = 1.f / (redl[0][0][rr] + redl[1][0][rr] + redl[2][0][rr] + redl[3][0][rr]);
    il2[r] = 1.f / (redl[0][1][rr] + redl[1][1][rr] + redl[2][1][rr] + redl[3][1][rr]);
  }

  floatx4 accO[4];
#pragma unroll
  for (int nt = 0; nt < 4; nt++) accO[nt] = zero;

  float* dwbase = diffw + (((size_t)bh) << 20) + (size_t)r0 * 1024 + cbase;

#pragma unroll
  for (int c2 = 0; c2 < 8; c2++) {
#pragma unroll
    for (int cc = 0; cc < 2; cc++) {
      int ct = c2 * 2 + cc;
#pragma unroll
      for (int r = 0; r < 4; r++) {
        float p1 = s1a[ct][r] * il1[r];
        float p2 = s2a[ct][r] * il2[r];
        float d = p1 - lam * p2;
        dwbase[(size_t)(quad * 4 + r) * 1024 + ct * 16 + lrow] = d;
        dsA[w][quad * 4 + r][cc * 16 + lrow] = f2bf(d);
      }
    }
    // same-wave LDS round trip: C-layout diff -> A-operand layout
    short8 ad = *(const short8*)(&dsA[w][lrow][quad * 8]);
#pragma unroll
    for (int nt = 0; nt < 4; nt++) {
      short8 bv = *(const short8*)(vth + (size_t)(nt * 16 + lrow) * 1024 + cbase + c2 * 32 + quad * 8);
      accO[nt] = MFMA16(ad, bv, accO[nt]);
    }
  }

  // block-reduce partial O across 4 waves + RMSNorm + store
#pragma unroll
  for (int nt = 0; nt < 4; nt++)
#pragma unroll
    for (int r = 0; r < 4; r++)
      ored[w][quad * 4 + r][nt * 16 + lrow] = accO[nt][r];
  __syncthreads();

#pragma unroll
  for (int rr = 0; rr < 4; rr++) {
    int row = w * 4 + rr;
    float o = ored[0][row][lane] + ored[1][row][lane] + ored[2][row][lane] + ored[3][row][lane];
    float ss = o * o;
#pragma unroll
    for (int off = 1; off < 64; off <<= 1) ss += __shfl_xor(ss, off);
    float rs = rsqrtf(ss * (1.f / 64.f) + 1e-5f);
    float v = o * rs * subln[lane] * ONE_MINUS_LAMBDA_F;
    attnb[((((size_t)b) << 10) + r0 + row) * 1024 + h * 64 + lane] = f2bf(v);
  }
}

extern "C" void kernel_launch(void* const* d_in, const int* in_sizes, int n_in,
                              void* d_out, int out_size, void* d_ws, size_t ws_size,
                              hipStream_t stream) {
  (void)in_sizes; (void)n_in; (void)out_size; (void)ws_size;
  const float* hs = (const float*)d_in[0];
  const float* q_w = (const float*)d_in[1];
  const float* q_b = (const float*)d_in[2];
  const float* k_w = (const float*)d_in[3];
  const float* k_b = (const float*)d_in[4];
  const float* v_w = (const float*)d_in[5];
  const float* v_b = (const float*)d_in[6];
  const float* o_w = (const float*)d_in[7];
  const float* o_b = (const float*)d_in[8];
  const float* lq1 = (const float*)d_in[9];
  const float* lk1 = (const float*)d_in[10];
  const float* lq2 = (const float*)d_in[11];
  const float* lk2 = (const float*)d_in[12];
  const float* subln = (const float*)d_in[13];

  char* ws = (char*)d_ws;
  unsigned short* hs_bf = (unsigned short*)(ws + 0);        // 8 MB (reused as attnb)
  unsigned short* attnb = (unsigned short*)(ws + 0);
  unsigned short* qw_bf = (unsigned short*)(ws + 8388608);  // 2 MB
  unsigned short* kw_bf = (unsigned short*)(ws + 10485760);
  unsigned short* vw_bf = (unsigned short*)(ws + 12582912);
  unsigned short* ow_bf = (unsigned short*)(ws + 14680064);
  unsigned short* q_h = (unsigned short*)(ws + 16777216);   // 8 MB
  unsigned short* k_h = (unsigned short*)(ws + 25165824);   // 8 MB
  unsigned short* v_nat = (unsigned short*)(ws + 33554432); // 8 MB
  unsigned short* v_t = (unsigned short*)(ws + 41943040);   // 8 MB

  cvt_f32_bf16<<<4096, 256, 0, stream>>>(hs, hs_bf, 1048576);
  cvt_f32_bf16<<<1024, 256, 0, stream>>>(q_w, qw_bf, 262144);
  cvt_f32_bf16<<<1024, 256, 0, stream>>>(k_w, kw_bf, 262144);
  cvt_f32_bf16<<<1024, 256, 0, stream>>>(v_w, vw_bf, 262144);
  cvt_f32_bf16<<<1024, 256, 0, stream>>>(o_w, ow_bf, 262144);

  gemm_qkv<<<dim3(24, 32), 256, 0, stream>>>(hs_bf, qw_bf, kw_bf, vw_bf,
                                             q_b, k_b, v_b, q_h, k_h, v_nat);

  transpose_v<<<dim3(16, 64), 256, 0, stream>>>(v_nat, v_t);

  float* outf = (float*)d_out;
  attn_fused<<<4096, 256, 0, stream>>>(q_h, k_h, v_t, lq1, lk1, lq2, lk2, subln,
                                       outf + 4194304, attnb);

  gemm_o<<<dim3(8, 32), 256, 0, stream>>>(attnb, ow_bf, o_b, outf);
}